// Round 9
// baseline (235.329 us; speedup 1.0000x reference)
//
#include <hip/hip_runtime.h>
#include <cstdint>

typedef unsigned short u16;
typedef __bf16  bf16x8 __attribute__((ext_vector_type(8)));
typedef unsigned short u16x8 __attribute__((ext_vector_type(8)));
typedef unsigned short u16x4 __attribute__((ext_vector_type(4)));
typedef short s16x4 __attribute__((ext_vector_type(4)));
typedef float   f32x4  __attribute__((ext_vector_type(4)));

#define LOG2E 1.44269504088896340736f

__device__ __forceinline__ u16 f2b(float f) {
  union { __bf16 h; u16 u; } c; c.h = (__bf16)f;   // native v_cvt (RNE) on gfx950
  return c.u;
}

// Granule (16B) XOR swizzle for [rows][64]-bf16 LDS tiles.
__device__ __forceinline__ int swz(int row) { return (row & 7) ^ ((row >> 3) & 7); }
__device__ __forceinline__ int sidx(int row, int k) {
  return row * 64 + ((((k >> 3) ^ swz(row)) & 7) << 3) + (k & 7);
}
__device__ __forceinline__ bf16x8 ld_frag(const u16* base, int row, int k) {
  return *(const bf16x8*)(base + sidx(row, k));
}

// async global->LDS, 16B/lane; LDS dest wave-uniform base (+lane*16 implicit)
__device__ __forceinline__ void async16(const u16* g, u16* l) {
  __builtin_amdgcn_global_load_lds(
      (__attribute__((address_space(1))) unsigned int*)(uintptr_t)g,
      (__attribute__((address_space(3))) unsigned int*)(uintptr_t)l,
      16, 0, 0);
}

// ---------------- fp32 -> bf16 weight conversion ----------------
__global__ __launch_bounds__(256) void cvt_kernel(
    const float* __restrict__ w0, const float* __restrict__ w1,
    const float* __restrict__ w2, const float* __restrict__ w3,
    u16* __restrict__ dst) {
  const float* src = (blockIdx.y == 0) ? w0 : (blockIdx.y == 1) ? w1
                   : (blockIdx.y == 2) ? w2 : w3;
  const int idx = (blockIdx.x * 256 + threadIdx.x) * 4;
  f32x4 v = *(const f32x4*)(src + idx);
  u16x4 o;
#pragma unroll
  for (int j = 0; j < 4; ++j) o[j] = f2b(v[j]);
  *(u16x4*)(dst + (size_t)blockIdx.y * 1048576 + idx) = o;
}

// ---------------- LayerNorm: fp32 in, bf16 out ----------------
__global__ __launch_bounds__(256) void ln_kernel(
    const float* __restrict__ hs, const float* __restrict__ gamma,
    const float* __restrict__ beta, u16* __restrict__ X) {
  __shared__ float red[8];
  const int row = blockIdx.x;
  const int tid = threadIdx.x;
  f32x4 v = *(const f32x4*)(hs + (size_t)row * 1024 + tid * 4);
  float s = 0.f, s2 = 0.f;
#pragma unroll
  for (int j = 0; j < 4; ++j) { s += v[j]; s2 += v[j] * v[j]; }
#pragma unroll
  for (int o = 1; o < 64; o <<= 1) { s += __shfl_xor(s, o); s2 += __shfl_xor(s2, o); }
  const int wid = tid >> 6, lane = tid & 63;
  if (lane == 0) { red[wid] = s; red[4 + wid] = s2; }
  __syncthreads();
  s  = red[0] + red[1] + red[2] + red[3];
  s2 = red[4] + red[5] + red[6] + red[7];
  const float mean = s * (1.f / 1024.f);
  const float var  = fmaxf(s2 * (1.f / 1024.f) - mean * mean, 0.f);
  const float rstd = rsqrtf(var + 1e-12f);
  f32x4 g = *(const f32x4*)(gamma + tid * 4);
  f32x4 bb = *(const f32x4*)(beta + tid * 4);
  u16x4 outv;
#pragma unroll
  for (int j = 0; j < 4; ++j) outv[j] = f2b((v[j] - mean) * rstd * g[j] + bb[j]);
  *(u16x4*)(X + (size_t)row * 1024 + tid * 4) = outv;
}

// ---------------- 128x128 gemm_bt tile (K=1024), async global->LDS staging ----------------
// MODE 0: bf16 out. MODE 1: fp32 out + fp32 residual.
// MODE 2: V-transpose out via LDS transpose -> coalesced 128B row writes.
template <int MODE>
__device__ __forceinline__ void gemm_tile_128(
    const u16* __restrict__ A, const u16* __restrict__ Bt,
    const float* __restrict__ bias, const float* __restrict__ res,
    void* __restrict__ Cv, int ldc, int m0, int nG) {
  __shared__ __align__(16) u16 As[128 * 64];
  __shared__ __align__(16) u16 Bs[128 * 64];
  const int tid = threadIdx.x;
  const int wid = tid >> 6;
  const int lane = tid & 63;
  const int l15 = lane & 15, lq = lane >> 4;
  const int wm = (wid & 1) << 6, wn = (wid >> 1) << 6;
  const int srow = tid >> 3;
  const int sg = tid & 7;

  f32x4 acc[4][4] = {};

  for (int k0 = 0; k0 < 1024; k0 += 64) {
#pragma unroll
    for (int i = 0; i < 4; ++i) {
      int row = (i << 5) + srow;
      int kc  = k0 + (((sg ^ swz(row)) & 7) << 3);
      async16(A + (size_t)row * 1024 + kc, As + (i << 11) + (wid << 9));
    }
#pragma unroll
    for (int i = 0; i < 4; ++i) {
      int row = (i << 5) + srow;
      int kc  = k0 + (((sg ^ swz(row)) & 7) << 3);
      async16(Bt + (size_t)row * 1024 + kc, Bs + (i << 11) + (wid << 9));
    }
    __syncthreads();
#pragma unroll
    for (int kk = 0; kk < 2; ++kk) {
      bf16x8 af[4], bf[4];
#pragma unroll
      for (int mi = 0; mi < 4; ++mi) af[mi] = ld_frag(As, wm + (mi << 4) + l15, (kk << 5) + (lq << 3));
#pragma unroll
      for (int ni = 0; ni < 4; ++ni) bf[ni] = ld_frag(Bs, wn + (ni << 4) + l15, (kk << 5) + (lq << 3));
#pragma unroll
      for (int mi = 0; mi < 4; ++mi)
#pragma unroll
        for (int ni = 0; ni < 4; ++ni)
          acc[mi][ni] = __builtin_amdgcn_mfma_f32_16x16x32_bf16(af[mi], bf[ni], acc[mi][ni], 0, 0, 0);
    }
    __syncthreads();
  }

  if (MODE == 2) {
    // V-transpose epilogue: per-wave 64x64 subtile -> LDS [n][m] -> coalesced VT rows.
    u16* Rg = (wid < 2 ? As : Bs) + ((wid & 1) << 12);   // 4096 u16 per wave region
#pragma unroll
    for (int ni = 0; ni < 4; ++ni) {
      const float bv = bias[wn + (ni << 4) + l15];
#pragma unroll
      for (int mi = 0; mi < 4; ++mi) {
        u16x4 pk;
#pragma unroll
        for (int r = 0; r < 4; ++r) pk[r] = f2b(acc[mi][ni][r] + bv);
        *(u16x4*)(Rg + sidx((ni << 4) + l15, (mi << 4) + (lq << 2))) = pk;
      }
    }
    __asm__ volatile("" ::: "memory");   // same-wave DS in-order
    const int rrow = lane >> 3;          // 0..7
    const int rg8  = (lane & 7) << 3;    // granule offset in k
    const int mg0 = m0 + wm;             // multiple of 64 -> single batch
    const int bb = mg0 >> 11, ss0 = mg0 & 2047;
    const int hh = (nG + wn) >> 6;       // head (nG+wn multiple of 64)
    u16* vbase = (u16*)Cv + ((size_t)((bb << 4) + hh) * 64) * 2048 + ss0;
#pragma unroll
    for (int p = 0; p < 8; ++p) {
      const int nl = (p << 3) + rrow;    // d within head
      bf16x8 rowv = ld_frag(Rg, nl, rg8);
      *(bf16x8*)(vbase + (size_t)nl * 2048 + rg8) = rowv;
    }
  } else {
#pragma unroll
    for (int ni = 0; ni < 4; ++ni) {
      const int n = wn + (ni << 4) + l15;
      const float bv = bias[n];
#pragma unroll
      for (int mi = 0; mi < 4; ++mi) {
#pragma unroll
        for (int r = 0; r < 4; ++r) {
          const int m = wm + (mi << 4) + (lq << 2) + r;
          float v = acc[mi][ni][r] + bv;
          if (MODE == 1) {
            v += res[(size_t)m * ldc + n];
            ((float*)Cv)[(size_t)m * ldc + n] = v;
          } else {
            ((u16*)Cv)[(size_t)m * ldc + n] = f2b(v);
          }
        }
      }
    }
  }
}

// fused QKV: X @ {wq,wk}^T -> QK[4096x2048]; X @ wv^T -> VT[(b,h,d)][s]
__global__ __launch_bounds__(256, 3) void qkv_kernel(
    const u16* __restrict__ X, const u16* __restrict__ W,
    const float* __restrict__ bq, const float* __restrict__ bk, const float* __restrict__ bv,
    u16* __restrict__ QK, u16* __restrict__ VT) {
  const int n0 = blockIdx.x << 7;
  const int m0 = blockIdx.y << 7;
  const int wsel = n0 >> 10;
  const int nloc = n0 & 1023;
  const u16* Bt = W + (size_t)wsel * 1048576 + (size_t)nloc * 1024;
  if (wsel < 2) {
    const float* bias = (wsel == 0 ? bq : bk) + nloc;
    gemm_tile_128<0>(X + (size_t)m0 * 1024, Bt, bias, nullptr,
                     QK + (size_t)m0 * 2048 + n0, 2048, 0, 0);
  } else {
    gemm_tile_128<2>(X + (size_t)m0 * 1024, Bt, bv + nloc, nullptr,
                     VT, 0, m0, nloc);
  }
}

// O-proj + bias + residual(fp32) -> OUT fp32
__global__ __launch_bounds__(256, 3) void out_kernel(
    const u16* __restrict__ CTX, const u16* __restrict__ wo,
    const float* __restrict__ bo, const float* __restrict__ res, float* __restrict__ OUT) {
  const int n0 = blockIdx.x << 7;
  const int m0 = blockIdx.y << 7;
  gemm_tile_128<1>(CTX + (size_t)m0 * 1024, wo + (size_t)n0 * 1024, bo + n0,
                   res + (size_t)m0 * 1024 + n0, OUT + (size_t)m0 * 1024 + n0, 1024, 0, 0);
}

// ---------------- flash attention v6: direct-feed P via K=16 MFMA (no P LDS round-trip) ----
// S^T D-layout (row=key=(lane>>4)*4+r, col=q=lane&15) IS the B-operand layout of
// v_mfma_f32_16x16x16_bf16 (B[k=(lane>>4)*4+j][n=lane&15]) within each 16-key group,
// so softmaxed P feeds PV directly from registers.
__global__ __launch_bounds__(256, 2) void attn_kernel(
    const u16* __restrict__ QK, const u16* __restrict__ VT,
    const float* __restrict__ mask, u16* __restrict__ CTX) {
  __shared__ __align__(16) u16 Ksb[2][64 * 64];
  __shared__ __align__(16) u16 Vtsb[2][64 * 64];
  const int tid = threadIdx.x;
  const int wid = tid >> 6;            // 0..3
  const int lane = tid & 63;
  const int l15 = lane & 15, lq = lane >> 4;
  const int qt = blockIdx.x, h = blockIdx.y, b = blockIdx.z;

  const int qbase = (b << 11) + (qt << 7) + (wid << 5);   // wave's first q (global row)
  const u16* Kbase  = QK + (size_t)(b << 11) * 2048 + 1024 + (h << 6);
  const u16* VTbase = VT + (size_t)(((b << 4) + h) << 6) * 2048;

  // Q fragments (B-operand layout for 16x16x32): qf[f][kc][j] = Q[q=f*16+l15][d=kc*32+lq*8+j]
  bf16x8 qf[2][2];
#pragma unroll
  for (int f = 0; f < 2; ++f)
#pragma unroll
    for (int kc = 0; kc < 2; ++kc)
      qf[f][kc] = *(const bf16x8*)(QK + (size_t)(qbase + (f << 4) + l15) * 2048 + (h << 6) + (kc << 5) + (lq << 3));

  f32x4 cacc[2][4] = {};               // [qfrag][dm]: ctx^T rows d=dm*16+lq*4+r, col q=l15
  float l_run[2] = {0.f, 0.f};         // per-lane partial denominator (16 keys/iter)

  // staging: wave stages two 8-row chunks of each 64x64 tile
  const int sg = lane & 7;
  const int srow0 = (wid << 4) + (lane >> 3);
  const int srow1 = srow0 + 8;
  const int gk0 = ((sg ^ swz(srow0)) & 7) << 3;
  const int gk1 = ((sg ^ swz(srow1)) & 7) << 3;
  const int ld0 = ((wid << 1) + 0) << 9;
  const int ld1 = ((wid << 1) + 1) << 9;

  async16(Kbase + (size_t)srow0 * 2048 + gk0, &Ksb[0][0] + ld0);
  async16(Kbase + (size_t)srow1 * 2048 + gk1, &Ksb[0][0] + ld1);
  async16(VTbase + (size_t)srow0 * 2048 + gk0, &Vtsb[0][0] + ld0);
  async16(VTbase + (size_t)srow1 * 2048 + gk1, &Vtsb[0][0] + ld1);

  for (int kt = 0; kt < 32; ++kt) {
    const u16* Ks  = &Ksb[kt & 1][0];
    const u16* Vts = &Vtsb[kt & 1][0];
    __syncthreads();
    if (kt + 1 < 32) {
      const int nk = (kt + 1) << 6;
      async16(Kbase + (size_t)(nk + srow0) * 2048 + gk0, &Ksb[(kt + 1) & 1][0] + ld0);
      async16(Kbase + (size_t)(nk + srow1) * 2048 + gk1, &Ksb[(kt + 1) & 1][0] + ld1);
      async16(VTbase + (size_t)srow0 * 2048 + nk + gk0, &Vtsb[(kt + 1) & 1][0] + ld0);
      async16(VTbase + (size_t)srow1 * 2048 + nk + gk1, &Vtsb[(kt + 1) & 1][0] + ld1);
    }

    // S^T = K Q^T : sacc[f][ki] rows key=ki*16+lq*4+r, col q=l15
    f32x4 sacc[2][4] = {};
#pragma unroll
    for (int kc = 0; kc < 2; ++kc) {
      bf16x8 kf[4];
#pragma unroll
      for (int ki = 0; ki < 4; ++ki) kf[ki] = ld_frag(Ks, (ki << 4) + l15, (kc << 5) + (lq << 3));
#pragma unroll
      for (int f = 0; f < 2; ++f)
#pragma unroll
        for (int ki = 0; ki < 4; ++ki)
          sacc[f][ki] = __builtin_amdgcn_mfma_f32_16x16x32_bf16(kf[ki], qf[f][kc], sacc[f][ki], 0, 0, 0);
    }

    // mask in log2 domain
    f32x4 mvl[4];
#pragma unroll
    for (int ki = 0; ki < 4; ++ki) {
      f32x4 mv = *(const f32x4*)(mask + (b << 11) + (kt << 6) + (ki << 4) + (lq << 2));
#pragma unroll
      for (int r = 0; r < 4; ++r) mvl[ki][r] = mv[r] * LOG2E;
    }

    // p = 2^(s/8*log2e + m*log2e): lane-local, packed straight into B-operand frags
    s16x4 pf[2][4];
#pragma unroll
    for (int f = 0; f < 2; ++f) {
      float rs = 0.f;
#pragma unroll
      for (int ki = 0; ki < 4; ++ki) {
#pragma unroll
        for (int r = 0; r < 4; ++r) {
          float pv = __builtin_amdgcn_exp2f(sacc[f][ki][r] * (0.125f * LOG2E) + mvl[ki][r]);
          rs += pv;
          pf[f][ki][r] = (short)f2b(pv);
        }
      }
      l_run[f] += rs;
    }

    // ctx^T += V^T P : A=V^T frag (b64), B=pf (in-register), K=16 per key-group
#pragma unroll
    for (int ki = 0; ki < 4; ++ki) {
      s16x4 vf[4];
#pragma unroll
      for (int dm = 0; dm < 4; ++dm)
        vf[dm] = *(const s16x4*)(Vts + sidx((dm << 4) + l15, (ki << 4) + (lq << 2)));
#pragma unroll
      for (int dm = 0; dm < 4; ++dm)
#pragma unroll
        for (int f = 0; f < 2; ++f)
          cacc[f][dm] = __builtin_amdgcn_mfma_f32_16x16x16bf16_1k(vf[dm], pf[f][ki], cacc[f][dm], 0, 0, 0);
    }
  }

  // epilogue: complete the denominator (one cross-lane reduce per frag), write ctx
#pragma unroll
  for (int f = 0; f < 2; ++f) {
    float rs = l_run[f];
    rs += __shfl_xor(rs, 16);
    rs += __shfl_xor(rs, 32);
    const float inv = 1.0f / rs;
    u16* Crow = CTX + (size_t)(qbase + (f << 4) + l15) * 1024 + (h << 6);
#pragma unroll
    for (int dm = 0; dm < 4; ++dm) {
      u16x4 o;
#pragma unroll
      for (int r = 0; r < 4; ++r) o[r] = f2b(cacc[f][dm][r] * inv);
      *(u16x4*)(Crow + (dm << 4) + (lq << 2)) = o;
    }
  }
}

extern "C" void kernel_launch(void* const* d_in, const int* in_sizes, int n_in,
                              void* d_out, int out_size, void* d_ws, size_t ws_size,
                              hipStream_t stream) {
  const float* hs   = (const float*)d_in[0];
  const float* mask = (const float*)d_in[1];
  const float* wq   = (const float*)d_in[2];
  const float* bq   = (const float*)d_in[3];
  const float* wk   = (const float*)d_in[4];
  const float* bk   = (const float*)d_in[5];
  const float* wv   = (const float*)d_in[6];
  const float* bv   = (const float*)d_in[7];
  const float* wo   = (const float*)d_in[8];
  const float* bo   = (const float*)d_in[9];
  const float* lg   = (const float*)d_in[10];
  const float* lb   = (const float*)d_in[11];

  u16* X   = (u16*)d_ws;                       // 4096x1024 bf16   (8 MiB)
  u16* QK  = X + (size_t)4096 * 1024;          // 4096x2048 bf16   (16 MiB)
  u16* CTX = QK + (size_t)4096 * 2048;         // 4096x1024 bf16   (8 MiB)
  u16* W   = CTX + (size_t)4096 * 1024;        // wq|wk|wv|wo bf16 (8 MiB)
  u16* VT  = W + (size_t)4 * 1048576;          // [b,h,d][s] bf16  (8 MiB)
  float* OUT = (float*)d_out;

  ln_kernel<<<4096, 256, 0, stream>>>(hs, lg, lb, X);
  cvt_kernel<<<dim3(1024, 4), 256, 0, stream>>>(wq, wk, wv, wo, W);
  qkv_kernel<<<dim3(24, 32), 256, 0, stream>>>(X, W, bq, bk, bv, QK, VT);
  attn_kernel<<<dim3(16, 16, 2), 256, 0, stream>>>(QK, VT, mask, CTX);
  out_kernel<<<dim3(8, 32), 256, 0, stream>>>(CTX, W + (size_t)3 * 1048576, bo, hs, OUT);
}

// Round 10
// 209.133 us; speedup vs baseline: 1.1253x; 1.1253x over previous
//
#include <hip/hip_runtime.h>
#include <cstdint>

typedef unsigned short u16;
typedef __bf16  bf16x8 __attribute__((ext_vector_type(8)));
typedef unsigned short u16x8 __attribute__((ext_vector_type(8)));
typedef unsigned short u16x4 __attribute__((ext_vector_type(4)));
typedef float   f32x4  __attribute__((ext_vector_type(4)));

#define LOG2E 1.44269504088896340736f

__device__ __forceinline__ u16 f2b(float f) {
  union { __bf16 h; u16 u; } c; c.h = (__bf16)f;   // native v_cvt (RNE) on gfx950
  return c.u;
}

// Granule (16B) XOR swizzle for [rows][64]-bf16 LDS tiles.
__device__ __forceinline__ int swz(int row) { return (row & 7) ^ ((row >> 3) & 7); }
__device__ __forceinline__ int sidx(int row, int k) {
  return row * 64 + ((((k >> 3) ^ swz(row)) & 7) << 3) + (k & 7);
}
__device__ __forceinline__ bf16x8 ld_frag(const u16* base, int row, int k) {
  return *(const bf16x8*)(base + sidx(row, k));
}

// async global->LDS, 16B/lane (attn staging only)
__device__ __forceinline__ void async16(const u16* g, u16* l) {
  __builtin_amdgcn_global_load_lds(
      (__attribute__((address_space(1))) unsigned int*)(uintptr_t)g,
      (__attribute__((address_space(3))) unsigned int*)(uintptr_t)l,
      16, 0, 0);
}

// ---------------- fused LayerNorm + weight conversion (one dispatch) ----------------
__global__ __launch_bounds__(256) void prep_kernel(
    const float* __restrict__ hs, const float* __restrict__ gamma,
    const float* __restrict__ beta, u16* __restrict__ X,
    const float* __restrict__ w0, const float* __restrict__ w1,
    const float* __restrict__ w2, const float* __restrict__ w3,
    u16* __restrict__ Wd) {
  const int tid = threadIdx.x;
  if (blockIdx.x >= 4096) {
    // weight cvt: 4096 blocks, each 1024 elems
    const int idx4 = blockIdx.x - 4096;
    const int mat = idx4 >> 10;
    const float* src = (mat == 0) ? w0 : (mat == 1) ? w1 : (mat == 2) ? w2 : w3;
    const int idx = ((idx4 & 1023) * 256 + tid) * 4;
    f32x4 v = *(const f32x4*)(src + idx);
    u16x4 o;
#pragma unroll
    for (int j = 0; j < 4; ++j) o[j] = f2b(v[j]);
    *(u16x4*)(Wd + (size_t)mat * 1048576 + idx) = o;
    return;
  }
  __shared__ float red[8];
  const int row = blockIdx.x;
  f32x4 v = *(const f32x4*)(hs + (size_t)row * 1024 + tid * 4);
  float s = 0.f, s2 = 0.f;
#pragma unroll
  for (int j = 0; j < 4; ++j) { s += v[j]; s2 += v[j] * v[j]; }
#pragma unroll
  for (int o = 1; o < 64; o <<= 1) { s += __shfl_xor(s, o); s2 += __shfl_xor(s2, o); }
  const int wid = tid >> 6, lane = tid & 63;
  if (lane == 0) { red[wid] = s; red[4 + wid] = s2; }
  __syncthreads();
  s  = red[0] + red[1] + red[2] + red[3];
  s2 = red[4] + red[5] + red[6] + red[7];
  const float mean = s * (1.f / 1024.f);
  const float var  = fmaxf(s2 * (1.f / 1024.f) - mean * mean, 0.f);
  const float rstd = rsqrtf(var + 1e-12f);
  f32x4 g = *(const f32x4*)(gamma + tid * 4);
  f32x4 bb = *(const f32x4*)(beta + tid * 4);
  u16x4 outv;
#pragma unroll
  for (int j = 0; j < 4; ++j) outv[j] = f2b((v[j] - mean) * rstd * g[j] + bb[j]);
  *(u16x4*)(X + (size_t)row * 1024 + tid * 4) = outv;
}

// ---------------- 128x128 gemm_bt tile (K=1024), software-pipelined staging ----------------
// Register prefetch issued during previous compute phase -> the compiler's vmcnt(0)
// drain at the barrier waits on loads issued ~a full compute phase earlier (hidden).
// MODE 0: bf16 out. MODE 1: fp32 out + fp32 residual. MODE 2: V-transpose out.
template <int MODE>
__device__ __forceinline__ void gemm_tile_128(
    const u16* __restrict__ A, const u16* __restrict__ Bt,
    const float* __restrict__ bias, const float* __restrict__ res,
    void* __restrict__ Cv, int ldc, int m0, int nG) {
  __shared__ __align__(16) u16 As[128 * 64];
  __shared__ __align__(16) u16 Bs[128 * 64];
  const int tid = threadIdx.x;
  const int wid = tid >> 6;
  const int lane = tid & 63;
  const int l15 = lane & 15, lq = lane >> 4;
  const int wm = (wid & 1) << 6, wn = (wid >> 1) << 6;
  const int srow = tid >> 3;   // 0..31
  const int sg = tid & 7;

  f32x4 acc[4][4] = {};
  u16x8 ar[4], br[4];

  // prefetch tile k0=0
#pragma unroll
  for (int i = 0; i < 4; ++i) {
    int row = (i << 5) + srow;
    ar[i] = *(const u16x8*)(A  + (size_t)row * 1024 + (sg << 3));
    br[i] = *(const u16x8*)(Bt + (size_t)row * 1024 + (sg << 3));
  }

  for (int k0 = 0; k0 < 1024; k0 += 64) {
    if (k0) __syncthreads();           // previous compute done with LDS
#pragma unroll
    for (int i = 0; i < 4; ++i) {
      int row = (i << 5) + srow;
      *(u16x8*)(As + sidx(row, sg << 3)) = ar[i];
      *(u16x8*)(Bs + sidx(row, sg << 3)) = br[i];
    }
    __syncthreads();                   // staged tile visible to all waves
    if (k0 + 64 < 1024) {              // prefetch next tile during compute
#pragma unroll
      for (int i = 0; i < 4; ++i) {
        int row = (i << 5) + srow;
        ar[i] = *(const u16x8*)(A  + (size_t)row * 1024 + k0 + 64 + (sg << 3));
        br[i] = *(const u16x8*)(Bt + (size_t)row * 1024 + k0 + 64 + (sg << 3));
      }
    }
#pragma unroll
    for (int kk = 0; kk < 2; ++kk) {
      bf16x8 af[4], bf[4];
#pragma unroll
      for (int mi = 0; mi < 4; ++mi) af[mi] = ld_frag(As, wm + (mi << 4) + l15, (kk << 5) + (lq << 3));
#pragma unroll
      for (int ni = 0; ni < 4; ++ni) bf[ni] = ld_frag(Bs, wn + (ni << 4) + l15, (kk << 5) + (lq << 3));
#pragma unroll
      for (int mi = 0; mi < 4; ++mi)
#pragma unroll
        for (int ni = 0; ni < 4; ++ni)
          acc[mi][ni] = __builtin_amdgcn_mfma_f32_16x16x32_bf16(af[mi], bf[ni], acc[mi][ni], 0, 0, 0);
    }
  }
  __syncthreads();   // last tile's LDS reads done before MODE 2 reuses As/Bs

  if (MODE == 2) {
    // V-transpose epilogue: per-wave 64x64 subtile -> LDS [n][m] -> coalesced VT rows.
    u16* Rg = (wid < 2 ? As : Bs) + ((wid & 1) << 12);
#pragma unroll
    for (int ni = 0; ni < 4; ++ni) {
      const float bv = bias[wn + (ni << 4) + l15];
#pragma unroll
      for (int mi = 0; mi < 4; ++mi) {
        u16x4 pk;
#pragma unroll
        for (int r = 0; r < 4; ++r) pk[r] = f2b(acc[mi][ni][r] + bv);
        *(u16x4*)(Rg + sidx((ni << 4) + l15, (mi << 4) + (lq << 2))) = pk;
      }
    }
    __asm__ volatile("" ::: "memory");   // same-wave DS in-order
    const int rrow = lane >> 3;
    const int rg8  = (lane & 7) << 3;
    const int mg0 = m0 + wm;
    const int bb = mg0 >> 11, ss0 = mg0 & 2047;
    const int hh = (nG + wn) >> 6;
    u16* vbase = (u16*)Cv + ((size_t)((bb << 4) + hh) * 64) * 2048 + ss0;
#pragma unroll
    for (int p = 0; p < 8; ++p) {
      const int nl = (p << 3) + rrow;
      bf16x8 rowv = ld_frag(Rg, nl, rg8);
      *(bf16x8*)(vbase + (size_t)nl * 2048 + rg8) = rowv;
    }
  } else {
#pragma unroll
    for (int ni = 0; ni < 4; ++ni) {
      const int n = wn + (ni << 4) + l15;
      const float bv = bias[n];
#pragma unroll
      for (int mi = 0; mi < 4; ++mi) {
#pragma unroll
        for (int r = 0; r < 4; ++r) {
          const int m = wm + (mi << 4) + (lq << 2) + r;
          float v = acc[mi][ni][r] + bv;
          if (MODE == 1) {
            v += res[(size_t)m * ldc + n];
            ((float*)Cv)[(size_t)m * ldc + n] = v;
          } else {
            ((u16*)Cv)[(size_t)m * ldc + n] = f2b(v);
          }
        }
      }
    }
  }
}

// fused QKV: X @ {wq,wk}^T -> QK[4096x2048]; X @ wv^T -> VT[(b,h,d)][s]
__global__ __launch_bounds__(256, 3) void qkv_kernel(
    const u16* __restrict__ X, const u16* __restrict__ W,
    const float* __restrict__ bq, const float* __restrict__ bk, const float* __restrict__ bv,
    u16* __restrict__ QK, u16* __restrict__ VT) {
  const int n0 = blockIdx.x << 7;
  const int m0 = blockIdx.y << 7;
  const int wsel = n0 >> 10;
  const int nloc = n0 & 1023;
  const u16* Bt = W + (size_t)wsel * 1048576 + (size_t)nloc * 1024;
  if (wsel < 2) {
    const float* bias = (wsel == 0 ? bq : bk) + nloc;
    gemm_tile_128<0>(X + (size_t)m0 * 1024, Bt, bias, nullptr,
                     QK + (size_t)m0 * 2048 + n0, 2048, 0, 0);
  } else {
    gemm_tile_128<2>(X + (size_t)m0 * 1024, Bt, bv + nloc, nullptr,
                     VT, 0, m0, nloc);
  }
}

// O-proj + bias + residual(fp32) -> OUT fp32
__global__ __launch_bounds__(256, 3) void out_kernel(
    const u16* __restrict__ CTX, const u16* __restrict__ wo,
    const float* __restrict__ bo, const float* __restrict__ res, float* __restrict__ OUT) {
  const int n0 = blockIdx.x << 7;
  const int m0 = blockIdx.y << 7;
  gemm_tile_128<1>(CTX + (size_t)m0 * 1024, wo + (size_t)n0 * 1024, bo + n0,
                   res + (size_t)m0 * 1024 + n0, OUT + (size_t)m0 * 1024 + n0, 1024, 0, 0);
}

// ---------------- flash attention (R8 version): no-max-sub softmax, dbuf K/V ----------------
__global__ __launch_bounds__(256, 2) void attn_kernel(
    const u16* __restrict__ QK, const u16* __restrict__ VT,
    const float* __restrict__ mask, u16* __restrict__ CTX) {
  __shared__ __align__(16) u16 Ksb[2][64 * 64];
  __shared__ __align__(16) u16 Vtsb[2][64 * 64];
  __shared__ __align__(16) u16 Ps[4 * 32 * 64];
  const int tid = threadIdx.x;
  const int wid = tid >> 6;            // 0..3
  const int lane = tid & 63;
  const int l15 = lane & 15, lq = lane >> 4;
  const int qt = blockIdx.x, h = blockIdx.y, b = blockIdx.z;

  const int qbase = (b << 11) + (qt << 7) + (wid << 5);
  const u16* Kbase  = QK + (size_t)(b << 11) * 2048 + 1024 + (h << 6);
  const u16* VTbase = VT + (size_t)(((b << 4) + h) << 6) * 2048;

  bf16x8 qf[2][2];
#pragma unroll
  for (int f = 0; f < 2; ++f)
#pragma unroll
    for (int kc = 0; kc < 2; ++kc)
      qf[f][kc] = *(const bf16x8*)(QK + (size_t)(qbase + (f << 4) + l15) * 2048 + (h << 6) + (kc << 5) + (lq << 3));

  f32x4 cacc[2][4] = {};
  float l_run[2] = {0.f, 0.f};

  const int sg = lane & 7;
  const int srow0 = (wid << 4) + (lane >> 3);
  const int srow1 = srow0 + 8;
  const int gk0 = ((sg ^ swz(srow0)) & 7) << 3;
  const int gk1 = ((sg ^ swz(srow1)) & 7) << 3;
  const int ld0 = ((wid << 1) + 0) << 9;
  const int ld1 = ((wid << 1) + 1) << 9;
  u16* Pw = Ps + (wid << 11);

  async16(Kbase + (size_t)srow0 * 2048 + gk0, &Ksb[0][0] + ld0);
  async16(Kbase + (size_t)srow1 * 2048 + gk1, &Ksb[0][0] + ld1);
  async16(VTbase + (size_t)srow0 * 2048 + gk0, &Vtsb[0][0] + ld0);
  async16(VTbase + (size_t)srow1 * 2048 + gk1, &Vtsb[0][0] + ld1);

  for (int kt = 0; kt < 32; ++kt) {
    const u16* Ks  = &Ksb[kt & 1][0];
    const u16* Vts = &Vtsb[kt & 1][0];
    __syncthreads();
    if (kt + 1 < 32) {
      const int nk = (kt + 1) << 6;
      async16(Kbase + (size_t)(nk + srow0) * 2048 + gk0, &Ksb[(kt + 1) & 1][0] + ld0);
      async16(Kbase + (size_t)(nk + srow1) * 2048 + gk1, &Ksb[(kt + 1) & 1][0] + ld1);
      async16(VTbase + (size_t)srow0 * 2048 + nk + gk0, &Vtsb[(kt + 1) & 1][0] + ld0);
      async16(VTbase + (size_t)srow1 * 2048 + nk + gk1, &Vtsb[(kt + 1) & 1][0] + ld1);
    }

    // S^T = K Q^T
    f32x4 sacc[2][4] = {};
#pragma unroll
    for (int kc = 0; kc < 2; ++kc) {
      bf16x8 kf[4];
#pragma unroll
      for (int ki = 0; ki < 4; ++ki) kf[ki] = ld_frag(Ks, (ki << 4) + l15, (kc << 5) + (lq << 3));
#pragma unroll
      for (int f = 0; f < 2; ++f)
#pragma unroll
        for (int ki = 0; ki < 4; ++ki)
          sacc[f][ki] = __builtin_amdgcn_mfma_f32_16x16x32_bf16(kf[ki], qf[f][kc], sacc[f][ki], 0, 0, 0);
    }

    f32x4 mvl[4];
#pragma unroll
    for (int ki = 0; ki < 4; ++ki) {
      f32x4 mv = *(const f32x4*)(mask + (b << 11) + (kt << 6) + (ki << 4) + (lq << 2));
#pragma unroll
      for (int r = 0; r < 4; ++r) mvl[ki][r] = mv[r] * LOG2E;
    }

#pragma unroll
    for (int f = 0; f < 2; ++f) {
      float rs = 0.f;
#pragma unroll
      for (int ki = 0; ki < 4; ++ki) {
#pragma unroll
        for (int r = 0; r < 4; ++r) {
          float pv = __builtin_amdgcn_exp2f(sacc[f][ki][r] * (0.125f * LOG2E) + mvl[ki][r]);
          sacc[f][ki][r] = pv;
          rs += pv;
        }
      }
      l_run[f] += rs;
#pragma unroll
      for (int ki = 0; ki < 4; ++ki) {
        u16x4 pk;
#pragma unroll
        for (int r = 0; r < 4; ++r) pk[r] = f2b(sacc[f][ki][r]);
        *(u16x4*)(Pw + sidx((f << 4) + l15, (ki << 4) + (lq << 2))) = pk;
      }
    }
    __asm__ volatile("" ::: "memory");

    // ctx^T += VT P^T
#pragma unroll
    for (int kc = 0; kc < 2; ++kc) {
      bf16x8 pf[2];
#pragma unroll
      for (int f = 0; f < 2; ++f) pf[f] = ld_frag(Pw, (f << 4) + l15, (kc << 5) + (lq << 3));
#pragma unroll
      for (int dm = 0; dm < 4; ++dm) {
        bf16x8 vf = ld_frag(Vts, (dm << 4) + l15, (kc << 5) + (lq << 3));
#pragma unroll
        for (int f = 0; f < 2; ++f)
          cacc[f][dm] = __builtin_amdgcn_mfma_f32_16x16x32_bf16(vf, pf[f], cacc[f][dm], 0, 0, 0);
      }
    }
  }

#pragma unroll
  for (int f = 0; f < 2; ++f) {
    float rs = l_run[f];
    rs += __shfl_xor(rs, 16);
    rs += __shfl_xor(rs, 32);
    const float inv = 1.0f / rs;
    u16* Crow = CTX + (size_t)(qbase + (f << 4) + l15) * 1024 + (h << 6);
#pragma unroll
    for (int dm = 0; dm < 4; ++dm) {
      u16x4 o;
#pragma unroll
      for (int r = 0; r < 4; ++r) o[r] = f2b(cacc[f][dm][r] * inv);
      *(u16x4*)(Crow + (dm << 4) + (lq << 2)) = o;
    }
  }
}

extern "C" void kernel_launch(void* const* d_in, const int* in_sizes, int n_in,
                              void* d_out, int out_size, void* d_ws, size_t ws_size,
                              hipStream_t stream) {
  const float* hs   = (const float*)d_in[0];
  const float* mask = (const float*)d_in[1];
  const float* wq   = (const float*)d_in[2];
  const float* bq   = (const float*)d_in[3];
  const float* wk   = (const float*)d_in[4];
  const float* bk   = (const float*)d_in[5];
  const float* wv   = (const float*)d_in[6];
  const float* bv   = (const float*)d_in[7];
  const float* wo   = (const float*)d_in[8];
  const float* bo   = (const float*)d_in[9];
  const float* lg   = (const float*)d_in[10];
  const float* lb   = (const float*)d_in[11];

  u16* X   = (u16*)d_ws;                       // 4096x1024 bf16   (8 MiB)
  u16* QK  = X + (size_t)4096 * 1024;          // 4096x2048 bf16   (16 MiB)
  u16* CTX = QK + (size_t)4096 * 2048;         // 4096x1024 bf16   (8 MiB)
  u16* W   = CTX + (size_t)4096 * 1024;        // wq|wk|wv|wo bf16 (8 MiB)
  u16* VT  = W + (size_t)4 * 1048576;          // [b,h,d][s] bf16  (8 MiB)
  float* OUT = (float*)d_out;

  prep_kernel<<<8192, 256, 0, stream>>>(hs, lg, lb, X, wq, wk, wv, wo, W);
  qkv_kernel<<<dim3(24, 32), 256, 0, stream>>>(X, W, bq, bk, bv, QK, VT);
  attn_kernel<<<dim3(16, 16, 2), 256, 0, stream>>>(QK, VT, mask, CTX);
  out_kernel<<<dim3(8, 32), 256, 0, stream>>>(CTX, W + (size_t)3 * 1048576, bo, hs, OUT);
}